// Round 1
// baseline (579.457 us; speedup 1.0000x reference)
//
#include <hip/hip_runtime.h>

constexpr int NN = 100000;
constexpr int CH = 128;
constexpr int NE = 625000;

// xt = x @ W^T + b ; write to ws (gather source) and out (residual init).
// Tile: 32 rows x 128 cols per block, per-thread 4x4 register tile.
__global__ __launch_bounds__(256) void gemm_bias_kernel(
    const float* __restrict__ x, const float* __restrict__ W,
    const float* __restrict__ b, float* __restrict__ ws, float* __restrict__ out)
{
    __shared__ float wt[128 * 128];   // wt[i*128+o] = W[o*128+i]
    __shared__ float xs[32 * 128];
    const int tid = threadIdx.x;
    const int row0 = blockIdx.x * 32;

    // Load W transposed. lane -> o assignment: LDS writes conflict-free
    // (consecutive lanes -> consecutive banks). Global reads are strided but
    // W is 64KB and L2/L3-hot after the first blocks.
    const float4* W4 = reinterpret_cast<const float4*>(W);
    #pragma unroll
    for (int it = 0; it < 16; ++it) {
        int idx = it * 256 + tid;
        int o = idx & 127;
        int g = idx >> 7;          // 0..31 (float4 group along i)
        float4 v = W4[o * 32 + g];
        wt[(g * 4 + 0) * 128 + o] = v.x;
        wt[(g * 4 + 1) * 128 + o] = v.y;
        wt[(g * 4 + 2) * 128 + o] = v.z;
        wt[(g * 4 + 3) * 128 + o] = v.w;
    }
    // Load x tile (natural layout, float4 coalesced)
    const float4* x4 = reinterpret_cast<const float4*>(x);
    #pragma unroll
    for (int it = 0; it < 4; ++it) {
        int idx = it * 256 + tid;
        int r = idx >> 5;
        int g = idx & 31;
        reinterpret_cast<float4*>(xs)[r * 32 + g] =
            x4[(size_t)(row0 + r) * 32 + g];
    }
    __syncthreads();

    const int tx = tid & 31, ty = tid >> 5;
    const int c0 = tx * 4, r0 = ty * 4;
    float4 bv = reinterpret_cast<const float4*>(b)[tx];
    float acc[4][4];
    #pragma unroll
    for (int rr = 0; rr < 4; ++rr) {
        acc[rr][0] = bv.x; acc[rr][1] = bv.y;
        acc[rr][2] = bv.z; acc[rr][3] = bv.w;
    }

    #pragma unroll 4
    for (int i = 0; i < 128; ++i) {
        float4 wv = *reinterpret_cast<const float4*>(&wt[i * 128 + c0]);
        #pragma unroll
        for (int rr = 0; rr < 4; ++rr) {
            float xv = xs[(r0 + rr) * 128 + i];   // broadcast within lane-group
            acc[rr][0] += xv * wv.x;
            acc[rr][1] += xv * wv.y;
            acc[rr][2] += xv * wv.z;
            acc[rr][3] += xv * wv.w;
        }
    }

    #pragma unroll
    for (int rr = 0; rr < 4; ++rr) {
        float4 v = make_float4(acc[rr][0], acc[rr][1], acc[rr][2], acc[rr][3]);
        size_t off = (size_t)(row0 + r0 + rr) * 128 + c0;
        *reinterpret_cast<float4*>(&ws[off]) = v;
        *reinterpret_cast<float4*>(&out[off]) = v;
    }
}

// One wave per edge; lane handles 2 channels. Gather xt[src] (512B row,
// coalesced across the wave), atomicAdd into out[dst].
__global__ __launch_bounds__(256) void scatter_kernel(
    const int* __restrict__ ei, const float* __restrict__ xt,
    float* __restrict__ out)
{
    const int gid = blockIdx.x * 256 + threadIdx.x;
    const int e = gid >> 6;
    if (e >= NE) return;
    const int lane = gid & 63;
    const int src = ei[e];
    const int dst = ei[NE + e];
    const int c = lane * 2;
    const float2 v = *reinterpret_cast<const float2*>(&xt[(size_t)src * CH + c]);
    atomicAdd(&out[(size_t)dst * CH + c],     v.x);
    atomicAdd(&out[(size_t)dst * CH + c + 1], v.y);
}

extern "C" void kernel_launch(void* const* d_in, const int* in_sizes, int n_in,
                              void* d_out, int out_size, void* d_ws, size_t ws_size,
                              hipStream_t stream) {
    const float* x  = (const float*)d_in[0];
    const int*   ei = (const int*)d_in[1];   // [2][NE], int32
    const float* W  = (const float*)d_in[2];
    const float* b  = (const float*)d_in[3];
    float* out = (float*)d_out;
    float* ws  = (float*)d_ws;               // xt: NN*CH fp32 = 51.2 MB

    gemm_bias_kernel<<<NN / 32, 256, 0, stream>>>(x, W, b, ws, out);

    const long long threads = (long long)NE * 64;
    scatter_kernel<<<(int)((threads + 255) / 256), 256, 0, stream>>>(ei, ws, out);
}

// Round 2
// 409.956 us; speedup vs baseline: 1.4135x; 1.4135x over previous
//
#include <hip/hip_runtime.h>

constexpr int NN = 100000;
constexpr int CH = 128;
constexpr int NE = 625000;

// ---------------- GEMM: xt = x @ W^T + b -> ws only ----------------
__global__ __launch_bounds__(256) void gemm_bias_kernel(
    const float* __restrict__ x, const float* __restrict__ W,
    const float* __restrict__ b, float* __restrict__ ws)
{
    __shared__ float wt[128 * 128];   // wt[i*128+o] = W[o*128+i]
    __shared__ float xs[32 * 128];
    const int tid = threadIdx.x;
    const int row0 = blockIdx.x * 32;

    const float4* W4 = reinterpret_cast<const float4*>(W);
    #pragma unroll
    for (int it = 0; it < 16; ++it) {
        int idx = it * 256 + tid;
        int o = idx & 127;
        int g = idx >> 7;
        float4 v = W4[o * 32 + g];
        wt[(g * 4 + 0) * 128 + o] = v.x;
        wt[(g * 4 + 1) * 128 + o] = v.y;
        wt[(g * 4 + 2) * 128 + o] = v.z;
        wt[(g * 4 + 3) * 128 + o] = v.w;
    }
    const float4* x4 = reinterpret_cast<const float4*>(x);
    #pragma unroll
    for (int it = 0; it < 4; ++it) {
        int idx = it * 256 + tid;
        int r = idx >> 5;
        int g = idx & 31;
        reinterpret_cast<float4*>(xs)[r * 32 + g] =
            x4[(size_t)(row0 + r) * 32 + g];
    }
    __syncthreads();

    const int tx = tid & 31, ty = tid >> 5;
    const int c0 = tx * 4, r0 = ty * 4;
    float4 bv = reinterpret_cast<const float4*>(b)[tx];
    float acc[4][4];
    #pragma unroll
    for (int rr = 0; rr < 4; ++rr) {
        acc[rr][0] = bv.x; acc[rr][1] = bv.y;
        acc[rr][2] = bv.z; acc[rr][3] = bv.w;
    }

    #pragma unroll 4
    for (int i = 0; i < 128; ++i) {
        float4 wv = *reinterpret_cast<const float4*>(&wt[i * 128 + c0]);
        #pragma unroll
        for (int rr = 0; rr < 4; ++rr) {
            float xv = xs[(r0 + rr) * 128 + i];
            acc[rr][0] += xv * wv.x;
            acc[rr][1] += xv * wv.y;
            acc[rr][2] += xv * wv.z;
            acc[rr][3] += xv * wv.w;
        }
    }

    #pragma unroll
    for (int rr = 0; rr < 4; ++rr) {
        float4 v = make_float4(acc[rr][0], acc[rr][1], acc[rr][2], acc[rr][3]);
        *reinterpret_cast<float4*>(&ws[(size_t)(row0 + r0 + rr) * 128 + c0]) = v;
    }
}

// ---------------- counting sort of edges by dst ----------------
__global__ __launch_bounds__(256) void hist_kernel(
    const int* __restrict__ ei, int* __restrict__ cnt)
{
    int e = blockIdx.x * 256 + threadIdx.x;
    if (e >= NE) return;
    atomicAdd(&cnt[ei[NE + e]], 1);
}

// single-block exclusive scan over NN counts -> offs[NN+1], cursor[NN]
__global__ __launch_bounds__(1024) void scan_kernel(
    const int* __restrict__ cnt, int* __restrict__ offs, int* __restrict__ cursor)
{
    __shared__ int sums[1024];
    const int t = threadIdx.x;
    const int CHUNK = (NN + 1023) / 1024;   // 98
    int beg = t * CHUNK;
    int end = min(beg + CHUNK, NN);
    int s = 0;
    for (int i = beg; i < end; ++i) s += cnt[i];
    sums[t] = s;
    __syncthreads();
    for (int off = 1; off < 1024; off <<= 1) {
        int v = (t >= off) ? sums[t - off] : 0;
        __syncthreads();
        sums[t] += v;
        __syncthreads();
    }
    int run = sums[t] - s;   // exclusive prefix
    for (int i = beg; i < end; ++i) {
        int c = cnt[i];
        offs[i] = run;
        cursor[i] = run;
        run += c;
    }
    if (end == NN) offs[NN] = run;   // all such threads write the same total
}

__global__ __launch_bounds__(256) void sort_kernel(
    const int* __restrict__ ei, int* __restrict__ cursor, int* __restrict__ srcs)
{
    int e = blockIdx.x * 256 + threadIdx.x;
    if (e >= NE) return;
    int src = ei[e];
    int dst = ei[NE + e];
    int pos = atomicAdd(&cursor[dst], 1);
    srcs[pos] = src;
}

// ---------------- gather-reduce: one wave per dst node ----------------
__global__ __launch_bounds__(256) void gather_kernel(
    const float* __restrict__ xt, const int* __restrict__ offs,
    const int* __restrict__ srcs, float* __restrict__ out)
{
    const int wid = (blockIdx.x * 256 + threadIdx.x) >> 6;
    if (wid >= NN) return;
    const int lane = threadIdx.x & 63;
    const int c = lane * 2;

    float2 acc = *reinterpret_cast<const float2*>(&xt[(size_t)wid * CH + c]);
    int i = offs[wid];
    const int end = offs[wid + 1];

    for (; i + 1 < end; i += 2) {
        int s0 = srcs[i], s1 = srcs[i + 1];
        float2 v0 = *reinterpret_cast<const float2*>(&xt[(size_t)s0 * CH + c]);
        float2 v1 = *reinterpret_cast<const float2*>(&xt[(size_t)s1 * CH + c]);
        acc.x += v0.x; acc.y += v0.y;
        acc.x += v1.x; acc.y += v1.y;
    }
    if (i < end) {
        int s0 = srcs[i];
        float2 v0 = *reinterpret_cast<const float2*>(&xt[(size_t)s0 * CH + c]);
        acc.x += v0.x; acc.y += v0.y;
    }
    *reinterpret_cast<float2*>(&out[(size_t)wid * CH + c]) = acc;
}

extern "C" void kernel_launch(void* const* d_in, const int* in_sizes, int n_in,
                              void* d_out, int out_size, void* d_ws, size_t ws_size,
                              hipStream_t stream) {
    const float* x  = (const float*)d_in[0];
    const int*   ei = (const int*)d_in[1];   // [2][NE] int32
    const float* W  = (const float*)d_in[2];
    const float* b  = (const float*)d_in[3];
    float* out = (float*)d_out;

    float* xt   = (float*)d_ws;                       // NN*CH floats = 51.2 MB
    int*   cnt  = (int*)(xt + (size_t)NN * CH);       // NN
    int*   offs = cnt + NN;                           // NN+1
    int*   cur  = offs + NN + 1;                      // NN
    int*   srcs = cur + NN;                           // NE

    gemm_bias_kernel<<<NN / 32, 256, 0, stream>>>(x, W, b, xt);

    hipMemsetAsync(cnt, 0, (size_t)NN * sizeof(int), stream);
    hist_kernel<<<(NE + 255) / 256, 256, 0, stream>>>(ei, cnt);
    scan_kernel<<<1, 1024, 0, stream>>>(cnt, offs, cur);
    sort_kernel<<<(NE + 255) / 256, 256, 0, stream>>>(ei, cur, srcs);
    gather_kernel<<<(NN * 64 + 255) / 256, 256, 0, stream>>>(xt, offs, srcs, out);
}

// Round 4
// 194.996 us; speedup vs baseline: 2.9716x; 2.1024x over previous
//
#include <hip/hip_runtime.h>

constexpr int NN = 100000;
constexpr int CH = 128;
constexpr int NE = 625000;
constexpr int NSCAN = (NN + 1023) / 1024;   // 98 scan blocks

// ---------------- GEMM: xt = x @ W^T + b -> ws only ----------------
__global__ __launch_bounds__(256) void gemm_bias_kernel(
    const float* __restrict__ x, const float* __restrict__ W,
    const float* __restrict__ b, float* __restrict__ ws)
{
    __shared__ float wt[128 * 128];   // wt[i*128+o] = W[o*128+i]
    __shared__ float xs[32 * 128];
    const int tid = threadIdx.x;
    const int row0 = blockIdx.x * 32;

    const float4* W4 = reinterpret_cast<const float4*>(W);
    #pragma unroll
    for (int it = 0; it < 16; ++it) {
        int idx = it * 256 + tid;
        int o = idx & 127;
        int g = idx >> 7;
        float4 v = W4[o * 32 + g];
        wt[(g * 4 + 0) * 128 + o] = v.x;
        wt[(g * 4 + 1) * 128 + o] = v.y;
        wt[(g * 4 + 2) * 128 + o] = v.z;
        wt[(g * 4 + 3) * 128 + o] = v.w;
    }
    const float4* x4 = reinterpret_cast<const float4*>(x);
    #pragma unroll
    for (int it = 0; it < 4; ++it) {
        int idx = it * 256 + tid;
        int r = idx >> 5;
        int g = idx & 31;
        reinterpret_cast<float4*>(xs)[r * 32 + g] =
            x4[(size_t)(row0 + r) * 32 + g];
    }
    __syncthreads();

    const int tx = tid & 31, ty = tid >> 5;
    const int c0 = tx * 4, r0 = ty * 4;
    float4 bv = reinterpret_cast<const float4*>(b)[tx];
    float acc[4][4];
    #pragma unroll
    for (int rr = 0; rr < 4; ++rr) {
        acc[rr][0] = bv.x; acc[rr][1] = bv.y;
        acc[rr][2] = bv.z; acc[rr][3] = bv.w;
    }

    #pragma unroll 4
    for (int i = 0; i < 128; ++i) {
        float4 wv = *reinterpret_cast<const float4*>(&wt[i * 128 + c0]);
        #pragma unroll
        for (int rr = 0; rr < 4; ++rr) {
            float xv = xs[(r0 + rr) * 128 + i];
            acc[rr][0] += xv * wv.x;
            acc[rr][1] += xv * wv.y;
            acc[rr][2] += xv * wv.z;
            acc[rr][3] += xv * wv.w;
        }
    }

    #pragma unroll
    for (int rr = 0; rr < 4; ++rr) {
        float4 v = make_float4(acc[rr][0], acc[rr][1], acc[rr][2], acc[rr][3]);
        *reinterpret_cast<float4*>(&ws[(size_t)(row0 + r0 + rr) * 128 + c0]) = v;
    }
}

// Zero cnt on the compute queue (no SDMA memset node in the graph).
__global__ __launch_bounds__(256) void zero_kernel(int* __restrict__ cnt)
{
    int i = blockIdx.x * 256 + threadIdx.x;
    if (i < NN) cnt[i] = 0;
}

// ---------------- counting sort of edges by dst ----------------
__global__ __launch_bounds__(256) void hist_kernel(
    const int* __restrict__ ei, int* __restrict__ cnt)
{
    int e = blockIdx.x * 256 + threadIdx.x;
    if (e >= NE) return;
    atomicAdd(&cnt[ei[NE + e]], 1);
}

// Step A: each block scans 1024 counts (256 thr x 4); local exclusive
// prefixes -> loff, block total -> blocksums.
__global__ __launch_bounds__(256) void scan_local_kernel(
    const int* __restrict__ cnt, int* __restrict__ loff,
    int* __restrict__ blocksums)
{
    __shared__ int tsum[256];
    const int t = threadIdx.x;
    const int base = blockIdx.x * 1024 + t * 4;
    int v[4];
    #pragma unroll
    for (int k = 0; k < 4; ++k) {
        int i = base + k;
        v[k] = (i < NN) ? cnt[i] : 0;
    }
    const int s = v[0] + v[1] + v[2] + v[3];
    tsum[t] = s;
    __syncthreads();
    for (int off = 1; off < 256; off <<= 1) {
        int u = (t >= off) ? tsum[t - off] : 0;
        __syncthreads();
        tsum[t] += u;
        __syncthreads();
    }
    int run = tsum[t] - s;   // exclusive thread prefix within block
    #pragma unroll
    for (int k = 0; k < 4; ++k) {
        int i = base + k;
        if (i < NN) loff[i] = run;
        run += v[k];
    }
    if (t == 255) blocksums[blockIdx.x] = tsum[255];
}

// Step B: exclusive scan of the 98 block sums (one small block).
__global__ __launch_bounds__(128) void scan_blocks_kernel(int* __restrict__ blocksums)
{
    __shared__ int sm[128];
    const int t = threadIdx.x;
    int v = (t < NSCAN) ? blocksums[t] : 0;
    sm[t] = v;
    __syncthreads();
    for (int off = 1; off < 128; off <<= 1) {
        int u = (t >= off) ? sm[t - off] : 0;
        __syncthreads();
        sm[t] += u;
        __syncthreads();
    }
    if (t < NSCAN) blocksums[t] = sm[t] - v;   // exclusive
}

// Step C (out-of-place): offs = loff + blockprefix; cursor = offs; offs[NN]=NE.
__global__ __launch_bounds__(256) void scan_add_kernel(
    const int* __restrict__ loff, const int* __restrict__ blocksums,
    int* __restrict__ offs, int* __restrict__ cursor)
{
    int i = blockIdx.x * 256 + threadIdx.x;
    if (i > NN) return;
    if (i == NN) { offs[NN] = NE; return; }
    int o = loff[i] + blocksums[i >> 10];
    offs[i] = o;
    cursor[i] = o;
}

__global__ __launch_bounds__(256) void sort_kernel(
    const int* __restrict__ ei, int* __restrict__ cursor, int* __restrict__ srcs)
{
    int e = blockIdx.x * 256 + threadIdx.x;
    if (e >= NE) return;
    int src = ei[e];
    int dst = ei[NE + e];
    int pos = atomicAdd(&cursor[dst], 1);
    srcs[pos] = src;
}

// ---------------- gather-reduce: one wave per dst node ----------------
__global__ __launch_bounds__(256) void gather_kernel(
    const float* __restrict__ xt, const int* __restrict__ offs,
    const int* __restrict__ srcs, float* __restrict__ out)
{
    const int wid = (blockIdx.x * 256 + threadIdx.x) >> 6;
    if (wid >= NN) return;
    const int lane = threadIdx.x & 63;
    const int c = lane * 2;

    float2 acc = *reinterpret_cast<const float2*>(&xt[(size_t)wid * CH + c]);
    int i = offs[wid];
    const int end = offs[wid + 1];

    for (; i + 1 < end; i += 2) {
        int s0 = srcs[i], s1 = srcs[i + 1];
        float2 v0 = *reinterpret_cast<const float2*>(&xt[(size_t)s0 * CH + c]);
        float2 v1 = *reinterpret_cast<const float2*>(&xt[(size_t)s1 * CH + c]);
        acc.x += v0.x; acc.y += v0.y;
        acc.x += v1.x; acc.y += v1.y;
    }
    if (i < end) {
        int s0 = srcs[i];
        float2 v0 = *reinterpret_cast<const float2*>(&xt[(size_t)s0 * CH + c]);
        acc.x += v0.x; acc.y += v0.y;
    }
    *reinterpret_cast<float2*>(&out[(size_t)wid * CH + c]) = acc;
}

extern "C" void kernel_launch(void* const* d_in, const int* in_sizes, int n_in,
                              void* d_out, int out_size, void* d_ws, size_t ws_size,
                              hipStream_t stream) {
    const float* x  = (const float*)d_in[0];
    const int*   ei = (const int*)d_in[1];   // [2][NE] int32
    const float* W  = (const float*)d_in[2];
    const float* b  = (const float*)d_in[3];
    float* out = (float*)d_out;

    float* xt    = (float*)d_ws;                      // NN*CH floats = 51.2 MB
    int*   cnt   = (int*)(xt + (size_t)NN * CH);      // NN
    int*   loff  = cnt + NN;                          // NN
    int*   offs  = loff + NN;                         // NN+1
    int*   cur   = offs + NN + 1;                     // NN
    int*   bsums = cur + NN;                          // 128
    int*   srcs  = bsums + 128;                       // NE (last)

    gemm_bias_kernel<<<NN / 32, 256, 0, stream>>>(x, W, b, xt);

    zero_kernel<<<(NN + 255) / 256, 256, 0, stream>>>(cnt);
    hist_kernel<<<(NE + 255) / 256, 256, 0, stream>>>(ei, cnt);
    scan_local_kernel<<<NSCAN, 256, 0, stream>>>(cnt, loff, bsums);
    scan_blocks_kernel<<<1, 128, 0, stream>>>(bsums);
    scan_add_kernel<<<(NN + 1 + 255) / 256, 256, 0, stream>>>(loff, bsums, offs, cur);
    sort_kernel<<<(NE + 255) / 256, 256, 0, stream>>>(ei, cur, srcs);
    gather_kernel<<<(NN * 64 + 255) / 256, 256, 0, stream>>>(xt, offs, srcs, out);
}

// Round 5
// 136.693 us; speedup vs baseline: 4.2391x; 1.4265x over previous
//
#include <hip/hip_runtime.h>

constexpr int NN = 100000;
constexpr int CH = 128;
constexpr int NE = 625000;
constexpr int NSCAN = (NN + 1023) / 1024;   // 98 scan blocks

typedef __bf16 bf16x8 __attribute__((ext_vector_type(8)));
typedef float  f32x4  __attribute__((ext_vector_type(4)));

// ---------------- MFMA GEMM: xt_bf16 = bf16(x @ W^T + b) ----------------
// 4 waves/block, 16 rows/wave, full 128 cols per wave.
// A frag: lane holds x[row0+(l&15)][ks*32+(l>>4)*8 + j], j=0..7
// B frag: lane holds W[c0+(l&15)][ks*32+(l>>4)*8 + j]  (B = W^T block)
// D:      col = l&15, row = (l>>4)*4 + reg   [m89-verified]
__global__ __launch_bounds__(256) void gemm_mfma_kernel(
    const float* __restrict__ x, const float* __restrict__ W,
    const float* __restrict__ b, __bf16* __restrict__ xt)
{
    // W staged as bf16, swizzled: wlds[col*128 + (k ^ ((col&7)<<3))]
    __shared__ __bf16 wlds[128 * 128];
    const int tid = threadIdx.x;

    const float4* W4 = reinterpret_cast<const float4*>(W);
    #pragma unroll
    for (int it = 0; it < 16; ++it) {
        int idx = it * 256 + tid;          // 4096 float4 groups, coalesced
        int col = idx >> 5;
        int k0  = (idx & 31) * 4;
        float4 v = W4[idx];
        __bf16* p = &wlds[col * 128 + (k0 ^ ((col & 7) << 3))];
        p[0] = (__bf16)v.x; p[1] = (__bf16)v.y;
        p[2] = (__bf16)v.z; p[3] = (__bf16)v.w;
    }
    __syncthreads();

    const int lane = tid & 63;
    const int lm = lane & 15;          // A-row / B-col / D-col within tile
    const int lk = lane >> 4;          // k-group
    const int row0 = blockIdx.x * 64 + (tid >> 6) * 16;

    int arow = row0 + lm;
    if (arow >= NN) arow = NN - 1;     // clamp; stores are predicated
    const float* xrow = x + (size_t)arow * CH;

    bf16x8 afrag[4];
    #pragma unroll
    for (int ks = 0; ks < 4; ++ks) {
        const float4* xr = reinterpret_cast<const float4*>(xrow + ks * 32 + lk * 8);
        float4 u = xr[0], v = xr[1];
        afrag[ks][0] = (__bf16)u.x; afrag[ks][1] = (__bf16)u.y;
        afrag[ks][2] = (__bf16)u.z; afrag[ks][3] = (__bf16)u.w;
        afrag[ks][4] = (__bf16)v.x; afrag[ks][5] = (__bf16)v.y;
        afrag[ks][6] = (__bf16)v.z; afrag[ks][7] = (__bf16)v.w;
    }

    #pragma unroll
    for (int t = 0; t < 8; ++t) {
        const int col = t * 16 + lm;
        float bc = b[col];
        f32x4 acc = {bc, bc, bc, bc};
        #pragma unroll
        for (int ks = 0; ks < 4; ++ks) {
            bf16x8 bfrag = *reinterpret_cast<const bf16x8*>(
                &wlds[col * 128 + ((ks * 32 + lk * 8) ^ ((col & 7) << 3))]);
            acc = __builtin_amdgcn_mfma_f32_16x16x32_bf16(afrag[ks], bfrag, acc, 0, 0, 0);
        }
        #pragma unroll
        for (int r = 0; r < 4; ++r) {
            int row = row0 + lk * 4 + r;
            if (row < NN)
                xt[(size_t)row * CH + col] = (__bf16)acc[r];
        }
    }
}

// Zero cnt on the compute queue (no SDMA memset node in the graph).
__global__ __launch_bounds__(256) void zero_kernel(int* __restrict__ cnt)
{
    int i = blockIdx.x * 256 + threadIdx.x;
    if (i < NN) cnt[i] = 0;
}

// ---------------- counting sort of edges by dst ----------------
__global__ __launch_bounds__(256) void hist_kernel(
    const int* __restrict__ ei, int* __restrict__ cnt)
{
    int e = blockIdx.x * 256 + threadIdx.x;
    if (e >= NE) return;
    atomicAdd(&cnt[ei[NE + e]], 1);
}

__global__ __launch_bounds__(256) void scan_local_kernel(
    const int* __restrict__ cnt, int* __restrict__ loff,
    int* __restrict__ blocksums)
{
    __shared__ int tsum[256];
    const int t = threadIdx.x;
    const int base = blockIdx.x * 1024 + t * 4;
    int v[4];
    #pragma unroll
    for (int k = 0; k < 4; ++k) {
        int i = base + k;
        v[k] = (i < NN) ? cnt[i] : 0;
    }
    const int s = v[0] + v[1] + v[2] + v[3];
    tsum[t] = s;
    __syncthreads();
    for (int off = 1; off < 256; off <<= 1) {
        int u = (t >= off) ? tsum[t - off] : 0;
        __syncthreads();
        tsum[t] += u;
        __syncthreads();
    }
    int run = tsum[t] - s;
    #pragma unroll
    for (int k = 0; k < 4; ++k) {
        int i = base + k;
        if (i < NN) loff[i] = run;
        run += v[k];
    }
    if (t == 255) blocksums[blockIdx.x] = tsum[255];
}

__global__ __launch_bounds__(128) void scan_blocks_kernel(int* __restrict__ blocksums)
{
    __shared__ int sm[128];
    const int t = threadIdx.x;
    int v = (t < NSCAN) ? blocksums[t] : 0;
    sm[t] = v;
    __syncthreads();
    for (int off = 1; off < 128; off <<= 1) {
        int u = (t >= off) ? sm[t - off] : 0;
        __syncthreads();
        sm[t] += u;
        __syncthreads();
    }
    if (t < NSCAN) blocksums[t] = sm[t] - v;
}

__global__ __launch_bounds__(256) void scan_add_kernel(
    const int* __restrict__ loff, const int* __restrict__ blocksums,
    int* __restrict__ offs, int* __restrict__ cursor)
{
    int i = blockIdx.x * 256 + threadIdx.x;
    if (i > NN) return;
    if (i == NN) { offs[NN] = NE; return; }
    int o = loff[i] + blocksums[i >> 10];
    offs[i] = o;
    cursor[i] = o;
}

__global__ __launch_bounds__(256) void sort_kernel(
    const int* __restrict__ ei, int* __restrict__ cursor, int* __restrict__ srcs)
{
    int e = blockIdx.x * 256 + threadIdx.x;
    if (e >= NE) return;
    int src = ei[e];
    int dst = ei[NE + e];
    int pos = atomicAdd(&cursor[dst], 1);
    srcs[pos] = src;
}

// ---------------- gather-reduce: one wave per dst node, bf16 rows ----------
__global__ __launch_bounds__(256) void gather_kernel(
    const uint* __restrict__ xtu,          // xt as bf16 pairs: [NN][64] uints
    const int* __restrict__ offs, const int* __restrict__ srcs,
    float* __restrict__ out)
{
    const int wid = (blockIdx.x * 256 + threadIdx.x) >> 6;
    if (wid >= NN) return;
    const int lane = threadIdx.x & 63;

    uint h = xtu[(size_t)wid * 64 + lane];  // own row (residual)
    float2 acc;
    acc.x = __uint_as_float(h << 16);
    acc.y = __uint_as_float(h & 0xffff0000u);

    int i = offs[wid];
    const int end = offs[wid + 1];

    for (; i + 3 < end; i += 4) {
        int s0 = srcs[i], s1 = srcs[i + 1], s2 = srcs[i + 2], s3 = srcs[i + 3];
        uint h0 = xtu[(size_t)s0 * 64 + lane];
        uint h1 = xtu[(size_t)s1 * 64 + lane];
        uint h2 = xtu[(size_t)s2 * 64 + lane];
        uint h3 = xtu[(size_t)s3 * 64 + lane];
        acc.x += __uint_as_float(h0 << 16);        acc.y += __uint_as_float(h0 & 0xffff0000u);
        acc.x += __uint_as_float(h1 << 16);        acc.y += __uint_as_float(h1 & 0xffff0000u);
        acc.x += __uint_as_float(h2 << 16);        acc.y += __uint_as_float(h2 & 0xffff0000u);
        acc.x += __uint_as_float(h3 << 16);        acc.y += __uint_as_float(h3 & 0xffff0000u);
    }
    for (; i < end; ++i) {
        uint h0 = xtu[(size_t)srcs[i] * 64 + lane];
        acc.x += __uint_as_float(h0 << 16);
        acc.y += __uint_as_float(h0 & 0xffff0000u);
    }
    reinterpret_cast<float2*>(out)[(size_t)wid * 64 + lane] = acc;
}

extern "C" void kernel_launch(void* const* d_in, const int* in_sizes, int n_in,
                              void* d_out, int out_size, void* d_ws, size_t ws_size,
                              hipStream_t stream) {
    const float* x  = (const float*)d_in[0];
    const int*   ei = (const int*)d_in[1];   // [2][NE] int32
    const float* W  = (const float*)d_in[2];
    const float* b  = (const float*)d_in[3];
    float* out = (float*)d_out;

    __bf16* xt   = (__bf16*)d_ws;                     // NN*CH bf16 = 25.6 MB
    int*   cnt   = (int*)(xt + (size_t)NN * CH);      // NN
    int*   loff  = cnt + NN;                          // NN
    int*   offs  = loff + NN;                         // NN+1
    int*   cur   = offs + NN + 1;                     // NN
    int*   bsums = cur + NN;                          // 128
    int*   srcs  = bsums + 128;                       // NE (last)

    gemm_mfma_kernel<<<(NN + 63) / 64, 256, 0, stream>>>(x, W, b, xt);

    zero_kernel<<<(NN + 255) / 256, 256, 0, stream>>>(cnt);
    hist_kernel<<<(NE + 255) / 256, 256, 0, stream>>>(ei, cnt);
    scan_local_kernel<<<NSCAN, 256, 0, stream>>>(cnt, loff, bsums);
    scan_blocks_kernel<<<1, 128, 0, stream>>>(bsums);
    scan_add_kernel<<<(NN + 1 + 255) / 256, 256, 0, stream>>>(loff, bsums, offs, cur);
    sort_kernel<<<(NE + 255) / 256, 256, 0, stream>>>(ei, cur, srcs);
    gather_kernel<<<(NN * 64 + 255) / 256, 256, 0, stream>>>(
        (const uint*)xt, offs, srcs, out);
}

// Round 6
// 109.662 us; speedup vs baseline: 5.2840x; 1.2465x over previous
//
#include <hip/hip_runtime.h>

constexpr int NN = 100000;
constexpr int CH = 128;
constexpr int NE = 625000;
constexpr int NSCAN = (NN + 1023) / 1024;          // 98 scan blocks
constexpr int GEMM_BLOCKS = (NN + 63) / 64;        // 1563
constexpr int HIST_BLOCKS = (NE / 4 + 255) / 256;  // 611 (NE % 4 == 0)

typedef __bf16 bf16x8 __attribute__((ext_vector_type(8)));
typedef float  f32x4  __attribute__((ext_vector_type(4)));

// ---- fused: MFMA GEMM (blocks < GEMM_BLOCKS) + edge histogram w/ rank ----
// GEMM: xt_bf16 = bf16(x @ W^T + b), 4 waves/block, 16 rows/wave.
// Hist: rank[e] = atomicAdd(&cnt[dst[e]], 1), 4 edges/thread (ILP-batched).
__global__ __launch_bounds__(256) void gemm_hist_kernel(
    const float* __restrict__ x, const float* __restrict__ W,
    const float* __restrict__ b, __bf16* __restrict__ xt,
    const int* __restrict__ ei, int* __restrict__ cnt, int* __restrict__ rank)
{
    if (blockIdx.x >= GEMM_BLOCKS) {
        const int t = (blockIdx.x - GEMM_BLOCKS) * 256 + threadIdx.x;
        if (t * 4 < NE) {
            int4 d = reinterpret_cast<const int4*>(ei + NE)[t];
            int r0 = atomicAdd(&cnt[d.x], 1);
            int r1 = atomicAdd(&cnt[d.y], 1);
            int r2 = atomicAdd(&cnt[d.z], 1);
            int r3 = atomicAdd(&cnt[d.w], 1);
            reinterpret_cast<int4*>(rank)[t] = make_int4(r0, r1, r2, r3);
        }
        return;
    }

    // W staged as bf16, swizzled: wlds[col*128 + (k ^ ((col&7)<<3))]
    __shared__ __bf16 wlds[128 * 128];
    const int tid = threadIdx.x;

    const float4* W4 = reinterpret_cast<const float4*>(W);
    #pragma unroll
    for (int it = 0; it < 16; ++it) {
        int idx = it * 256 + tid;          // 4096 float4 groups, coalesced
        int col = idx >> 5;
        int k0  = (idx & 31) * 4;
        float4 v = W4[idx];
        __bf16* p = &wlds[col * 128 + (k0 ^ ((col & 7) << 3))];
        p[0] = (__bf16)v.x; p[1] = (__bf16)v.y;
        p[2] = (__bf16)v.z; p[3] = (__bf16)v.w;
    }
    __syncthreads();

    const int lane = tid & 63;
    const int lm = lane & 15;          // A-row / B-col / D-col within tile
    const int lk = lane >> 4;          // k-group
    const int row0 = blockIdx.x * 64 + (tid >> 6) * 16;

    int arow = row0 + lm;
    if (arow >= NN) arow = NN - 1;     // clamp; stores are predicated
    const float* xrow = x + (size_t)arow * CH;

    bf16x8 afrag[4];
    #pragma unroll
    for (int ks = 0; ks < 4; ++ks) {
        const float4* xr = reinterpret_cast<const float4*>(xrow + ks * 32 + lk * 8);
        float4 u = xr[0], v = xr[1];
        afrag[ks][0] = (__bf16)u.x; afrag[ks][1] = (__bf16)u.y;
        afrag[ks][2] = (__bf16)u.z; afrag[ks][3] = (__bf16)u.w;
        afrag[ks][4] = (__bf16)v.x; afrag[ks][5] = (__bf16)v.y;
        afrag[ks][6] = (__bf16)v.z; afrag[ks][7] = (__bf16)v.w;
    }

    #pragma unroll
    for (int t = 0; t < 8; ++t) {
        const int col = t * 16 + lm;
        float bc = b[col];
        f32x4 acc = {bc, bc, bc, bc};
        #pragma unroll
        for (int ks = 0; ks < 4; ++ks) {
            bf16x8 bfrag = *reinterpret_cast<const bf16x8*>(
                &wlds[col * 128 + ((ks * 32 + lk * 8) ^ ((col & 7) << 3))]);
            acc = __builtin_amdgcn_mfma_f32_16x16x32_bf16(afrag[ks], bfrag, acc, 0, 0, 0);
        }
        #pragma unroll
        for (int r = 0; r < 4; ++r) {
            int row = row0 + lk * 4 + r;
            if (row < NN)
                xt[(size_t)row * CH + col] = (__bf16)acc[r];
        }
    }
}

// Zero cnt on the compute queue (no SDMA memset node in the graph).
__global__ __launch_bounds__(256) void zero_kernel(int* __restrict__ cnt)
{
    int i = blockIdx.x * 256 + threadIdx.x;
    if (i < NN) cnt[i] = 0;
}

__global__ __launch_bounds__(256) void scan_local_kernel(
    const int* __restrict__ cnt, int* __restrict__ loff,
    int* __restrict__ blocksums)
{
    __shared__ int tsum[256];
    const int t = threadIdx.x;
    const int base = blockIdx.x * 1024 + t * 4;
    int v[4];
    #pragma unroll
    for (int k = 0; k < 4; ++k) {
        int i = base + k;
        v[k] = (i < NN) ? cnt[i] : 0;
    }
    const int s = v[0] + v[1] + v[2] + v[3];
    tsum[t] = s;
    __syncthreads();
    for (int off = 1; off < 256; off <<= 1) {
        int u = (t >= off) ? tsum[t - off] : 0;
        __syncthreads();
        tsum[t] += u;
        __syncthreads();
    }
    int run = tsum[t] - s;
    #pragma unroll
    for (int k = 0; k < 4; ++k) {
        int i = base + k;
        if (i < NN) loff[i] = run;
        run += v[k];
    }
    if (t == 255) blocksums[blockIdx.x] = tsum[255];
}

__global__ __launch_bounds__(128) void scan_blocks_kernel(int* __restrict__ blocksums)
{
    __shared__ int sm[128];
    const int t = threadIdx.x;
    int v = (t < NSCAN) ? blocksums[t] : 0;
    sm[t] = v;
    __syncthreads();
    for (int off = 1; off < 128; off <<= 1) {
        int u = (t >= off) ? sm[t - off] : 0;
        __syncthreads();
        sm[t] += u;
        __syncthreads();
    }
    if (t < NSCAN) blocksums[t] = sm[t] - v;
}

__global__ __launch_bounds__(256) void scan_add_kernel(
    const int* __restrict__ loff, const int* __restrict__ blocksums,
    int* __restrict__ offs)
{
    int i = blockIdx.x * 256 + threadIdx.x;
    if (i > NN) return;
    if (i == NN) { offs[NN] = NE; return; }
    offs[i] = loff[i] + blocksums[i >> 10];
}

// Atomic-free placement: srcs[offs[dst] + rank[e]] = src, 4 edges/thread.
__global__ __launch_bounds__(256) void place_kernel(
    const int* __restrict__ ei, const int* __restrict__ rank,
    const int* __restrict__ offs, int* __restrict__ srcs)
{
    const int t = blockIdx.x * 256 + threadIdx.x;
    if (t * 4 >= NE) return;
    int4 s = reinterpret_cast<const int4*>(ei)[t];
    int4 d = reinterpret_cast<const int4*>(ei + NE)[t];
    int4 r = reinterpret_cast<const int4*>(rank)[t];
    int p0 = offs[d.x] + r.x;
    int p1 = offs[d.y] + r.y;
    int p2 = offs[d.z] + r.z;
    int p3 = offs[d.w] + r.w;
    srcs[p0] = s.x;
    srcs[p1] = s.y;
    srcs[p2] = s.z;
    srcs[p3] = s.w;
}

// ---------------- gather-reduce: one wave per dst node, bf16 rows ----------
__global__ __launch_bounds__(256) void gather_kernel(
    const uint* __restrict__ xtu,          // xt as bf16 pairs: [NN][64] uints
    const int* __restrict__ offs, const int* __restrict__ srcs,
    float* __restrict__ out)
{
    const int wid = (blockIdx.x * 256 + threadIdx.x) >> 6;
    if (wid >= NN) return;
    const int lane = threadIdx.x & 63;

    uint h = xtu[(size_t)wid * 64 + lane];  // own row (residual)
    float2 acc;
    acc.x = __uint_as_float(h << 16);
    acc.y = __uint_as_float(h & 0xffff0000u);

    int i = offs[wid];
    const int end = offs[wid + 1];

    for (; i + 3 < end; i += 4) {
        int s0 = srcs[i], s1 = srcs[i + 1], s2 = srcs[i + 2], s3 = srcs[i + 3];
        uint h0 = xtu[(size_t)s0 * 64 + lane];
        uint h1 = xtu[(size_t)s1 * 64 + lane];
        uint h2 = xtu[(size_t)s2 * 64 + lane];
        uint h3 = xtu[(size_t)s3 * 64 + lane];
        acc.x += __uint_as_float(h0 << 16);        acc.y += __uint_as_float(h0 & 0xffff0000u);
        acc.x += __uint_as_float(h1 << 16);        acc.y += __uint_as_float(h1 & 0xffff0000u);
        acc.x += __uint_as_float(h2 << 16);        acc.y += __uint_as_float(h2 & 0xffff0000u);
        acc.x += __uint_as_float(h3 << 16);        acc.y += __uint_as_float(h3 & 0xffff0000u);
    }
    for (; i < end; ++i) {
        uint h0 = xtu[(size_t)srcs[i] * 64 + lane];
        acc.x += __uint_as_float(h0 << 16);
        acc.y += __uint_as_float(h0 & 0xffff0000u);
    }
    reinterpret_cast<float2*>(out)[(size_t)wid * 64 + lane] = acc;
}

extern "C" void kernel_launch(void* const* d_in, const int* in_sizes, int n_in,
                              void* d_out, int out_size, void* d_ws, size_t ws_size,
                              hipStream_t stream) {
    const float* x  = (const float*)d_in[0];
    const int*   ei = (const int*)d_in[1];   // [2][NE] int32
    const float* W  = (const float*)d_in[2];
    const float* b  = (const float*)d_in[3];
    float* out = (float*)d_out;

    __bf16* xt   = (__bf16*)d_ws;                     // NN*CH bf16 = 25.6 MB
    int*   cnt   = (int*)(xt + (size_t)NN * CH);      // NN
    int*   loff  = cnt + NN;                          // NN
    int*   offs  = loff + NN;                         // NN+1
    int*   bsums = offs + NN + 1;                     // 128 (+pad to 16B)
    int*   rank  = bsums + 131;                       // NE
    int*   srcs  = rank + NE;                         // NE (last)

    zero_kernel<<<(NN + 255) / 256, 256, 0, stream>>>(cnt);
    gemm_hist_kernel<<<GEMM_BLOCKS + HIST_BLOCKS, 256, 0, stream>>>(
        x, W, b, xt, ei, cnt, rank);
    scan_local_kernel<<<NSCAN, 256, 0, stream>>>(cnt, loff, bsums);
    scan_blocks_kernel<<<1, 128, 0, stream>>>(bsums);
    scan_add_kernel<<<(NN + 1 + 255) / 256, 256, 0, stream>>>(loff, bsums, offs);
    place_kernel<<<HIST_BLOCKS, 256, 0, stream>>>(ei, rank, offs, srcs);
    gather_kernel<<<(NN * 64 + 255) / 256, 256, 0, stream>>>(
        (const uint*)xt, offs, srcs, out);
}